// Round 8
// baseline (226.820 us; speedup 1.0000x reference)
//
#include <hip/hip_runtime.h>
#include <hip/hip_bf16.h>

typedef _Float16 half8 __attribute__((ext_vector_type(8)));
typedef _Float16 half2v __attribute__((ext_vector_type(2)));
typedef __fp16 fp16x2 __attribute__((ext_vector_type(2)));
typedef float f32x4 __attribute__((ext_vector_type(4)));
typedef int i32x4 __attribute__((ext_vector_type(4)));

#define BH_ 64
#define L_ 1024
#define DK_ 64

__device__ __forceinline__ unsigned short f2h(float f) {
    _Float16 h = (_Float16)f;
    return __builtin_bit_cast(unsigned short, h);
}
__device__ __forceinline__ unsigned int pk2h(float a, float b) {
    fp16x2 h = __builtin_amdgcn_cvt_pkrtz(a, b);
    return __builtin_bit_cast(unsigned int, h);
}

// ---- inline-asm load/wait machinery. Order among asm volatile is pinned;
// literal vmcnt; sched_barrier(0) after each wait (rule #18).
// HARD CONSTRAINT learned in r7: peak live regs (in-flight dests + state)
// must fit the launch-bounds cap with slack, else spills race the loads.
template<int OFF>
__device__ __forceinline__ void gl_h8(half8& d, const unsigned short* p) {
    asm volatile("global_load_dwordx4 %0, %1, off offset:%2"
                 : "=&v"(d) : "v"(p), "n"(OFF));
}
template<int OFF>
__device__ __forceinline__ void gl_i4(i32x4& d, const int* p) {
    asm volatile("global_load_dwordx4 %0, %1, off offset:%2"
                 : "=&v"(d) : "v"(p), "n"(OFF));
}
template<int OFF>
__device__ __forceinline__ void gl_f4(f32x4& d, const float* p) {
    asm volatile("global_load_dwordx4 %0, %1, off offset:%2"
                 : "=&v"(d) : "v"(p), "n"(OFF));
}
template<int N>
__device__ __forceinline__ void wait_vm() {
    asm volatile("s_waitcnt vmcnt(%0)" :: "n"(N) : "memory");
    __builtin_amdgcn_sched_barrier(0);
}

// ---------------- prep: K -> fp16 ----------------
__global__ void prep_k(const float* __restrict__ K, unsigned short* __restrict__ Kh) {
    int idx = blockIdx.x * 256 + threadIdx.x;
    float4 v = reinterpret_cast<const float4*>(K)[idx];
    ushort4 o;
    o.x = f2h(v.x); o.y = f2h(v.y); o.z = f2h(v.z); o.w = f2h(v.w);
    reinterpret_cast<ushort4*>(Kh)[idx] = o;
}

// ---------------- prep: V -> Vt fp16 transposed [bh][n][k] ----------------
__global__ void prep_v(const float* __restrict__ V, unsigned short* __restrict__ Vt) {
    __shared__ float lds[64][65];
    int bh = blockIdx.x >> 4, kt = blockIdx.x & 15;
    int t = threadIdx.x;
    const float* Vb = V + ((size_t)bh * L_ + kt * 64) * DK_;
#pragma unroll
    for (int it = 0; it < 4; ++it) {
        int idx = it * 256 + t;
        int row = idx >> 4, c4 = idx & 15;
        float4 v = reinterpret_cast<const float4*>(Vb + (size_t)row * DK_)[c4];
        lds[row][c4 * 4 + 0] = v.x; lds[row][c4 * 4 + 1] = v.y;
        lds[row][c4 * 4 + 2] = v.z; lds[row][c4 * 4 + 3] = v.w;
    }
    __syncthreads();
    unsigned short* Vtb = Vt + (size_t)bh * 64 * L_ + kt * 64;
#pragma unroll
    for (int it = 0; it < 4; ++it) {
        int idx = it * 256 + t;
        int n = idx >> 4, c4 = idx & 15;
        ushort4 o;
        o.x = f2h(lds[c4 * 4 + 0][n]);
        o.y = f2h(lds[c4 * 4 + 1][n]);
        o.z = f2h(lds[c4 * 4 + 2][n]);
        o.w = f2h(lds[c4 * 4 + 3][n]);
        *reinterpret_cast<ushort4*>(Vtb + (size_t)n * L_ + c4 * 4) = o;
    }
}

// ---------------- main fused attention ----------------
// WG = 16 q-rows, 4 waves; wave w owns k in [w*256, w*256+256).
// Fine-grained pipeline: K chunks = 2 tiles (4 loads, dbuf), mask quarters
// (4 loads), V chunks = 4 loads (dbuf). Peak live ~97 regs < 128 cap.
__global__ __launch_bounds__(256, 4) void attn_main(
    const float* __restrict__ Q, const int* __restrict__ mask,
    const unsigned short* __restrict__ Kh, const unsigned short* __restrict__ Vt,
    float* __restrict__ ctx_out, float* __restrict__ attn_out)
{
    const int qt = blockIdx.x, bh = blockIdx.y;
    const int tid = threadIdx.x;
    const int w = tid >> 6;
    const int lane = tid & 63;
    const int lg = lane >> 4, lr = lane & 15;
    const int q0 = qt * 16;

    __shared__ float red[2][4][16];
    __shared__ union {
        unsigned short pbuf[4][640];
        float ctxbuf[4][16][68];
    } u;

    const size_t rowbase = ((size_t)bh * L_ + q0 + lr) * L_;
    const float* qp = Q + ((size_t)bh * L_ + q0 + lr) * DK_ + lg * 8;
    const int* mp = mask + rowbase + w * 256 + lg * 4;
    const unsigned short* kp = Kh + ((size_t)bh * L_ + w * 256 + lr) * DK_ + lg * 8;

    i32x4 mreg[8];
    half8 ka[2][2], kb[2][2];   // [buf][tile-in-chunk]; chunk = 2 tiles = 4 loads
    // K tile stride = 1024 shorts = 2048 B; chunk stride = 2048 shorts.
#define ISSUE_K2(BUF, C) { \
    const unsigned short* a_ = kp + (C) * 2048; \
    gl_h8<0>(ka[BUF][0], a_);    gl_h8<64>(kb[BUF][0], a_); \
    gl_h8<2048>(ka[BUF][1], a_); gl_h8<2112>(kb[BUF][1], a_); }
    // 4 mask tiles (rows of 16 ints per tile -> int4 per lane at tile*64B)
#define ISSUE_M4(IDX, T) { \
    gl_i4<(T) * 64 + 0>(mreg[(IDX) + 0], mp); \
    gl_i4<(T) * 64 + 64>(mreg[(IDX) + 1], mp); \
    gl_i4<(T) * 64 + 128>(mreg[(IDX) + 2], mp); \
    gl_i4<(T) * 64 + 192>(mreg[(IDX) + 3], mp); }
#define PACK_M4(DST, IDX) { \
    DST = 0; \
    _Pragma("unroll") \
    for (int t = 0; t < 4; ++t) \
        DST |= (unsigned(mreg[(IDX) + t][0] != 0) << (t * 4 + 0)) \
             | (unsigned(mreg[(IDX) + t][1] != 0) << (t * 4 + 1)) \
             | (unsigned(mreg[(IDX) + t][2] != 0) << (t * 4 + 2)) \
             | (unsigned(mreg[(IDX) + t][3] != 0) << (t * 4 + 3)); }

    // ---- QK prologue: MA(4) MB(4) Q(4) K0(4) K1(4) = 20 outstanding ----
    ISSUE_M4(0, 0);                          // FIFO: MA(4)
    ISSUE_M4(4, 4);                          // MA,MB (8)
    f32x4 qf0, qf1, qf2, qf3;
    gl_f4<0>(qf0, qp); gl_f4<16>(qf1, qp);
    gl_f4<128>(qf2, qp); gl_f4<144>(qf3, qp);// MA,MB,Q (12)
    ISSUE_K2(0, 0);                          // +K0 (16)
    ISSUE_K2(1, 1);                          // +K1 (20)

    unsigned int mwA, mwB, mwC, mwD, mw0, mw1;
    wait_vm<16>();                           // MA done
    PACK_M4(mwA, 0);
    wait_vm<12>();                           // MB done
    PACK_M4(mwB, 4);
    mw0 = mwA | (mwB << 16);                 // bit(tt*4+r), tt=0..7
    wait_vm<8>();                            // Q done
    half8 qh[2];
#pragma unroll
    for (int j = 0; j < 4; ++j) {
        qh[0][j]     = (_Float16)qf0[j];
        qh[0][j + 4] = (_Float16)qf1[j];
        qh[1][j]     = (_Float16)qf2[j];
        qh[1][j + 4] = (_Float16)qf3[j];
    }

    unsigned int sh[16][2];
    float mx = -INFINITY;
#define QK_TILE(BUF, T, TT, WORD) { \
    f32x4 acc_ = {0.f, 0.f, 0.f, 0.f}; \
    acc_ = __builtin_amdgcn_mfma_f32_16x16x32_f16(ka[BUF][T], qh[0], acc_, 0, 0, 0); \
    acc_ = __builtin_amdgcn_mfma_f32_16x16x32_f16(kb[BUF][T], qh[1], acc_, 0, 0, 0); \
    float s0_ = (((WORD) >> (((TT) & 7) * 4 + 0)) & 1u) ? -INFINITY : 0.25f * acc_[0]; \
    float s1_ = (((WORD) >> (((TT) & 7) * 4 + 1)) & 1u) ? -INFINITY : 0.25f * acc_[1]; \
    float s2_ = (((WORD) >> (((TT) & 7) * 4 + 2)) & 1u) ? -INFINITY : 0.25f * acc_[2]; \
    float s3_ = (((WORD) >> (((TT) & 7) * 4 + 3)) & 1u) ? -INFINITY : 0.25f * acc_[3]; \
    sh[TT][0] = pk2h(s0_, s1_); sh[TT][1] = pk2h(s2_, s3_); \
    mx = fmaxf(mx, fmaxf(fmaxf(s0_, s1_), fmaxf(s2_, s3_))); }
#define QK2(BUF, TT0, WORD) { \
    QK_TILE(BUF, 0, TT0, WORD); QK_TILE(BUF, 1, (TT0) + 1, WORD); }

    // ---- QK main: chunk Ci = tiles {2i, 2i+1}; dbuf; FIFO annotated ----
    wait_vm<4>();          // C0 done                  (4: C1)
    QK2(0, 0, mw0);
    ISSUE_K2(0, 2);        //                          (8: C1,C2)
    wait_vm<4>();          // C1 done                  (4: C2)
    QK2(1, 2, mw0);
    ISSUE_M4(0, 8);        // MC (tiles 8-11)          (8: C2,MC)
    ISSUE_K2(1, 3);        //                          (12: C2,MC,C3)
    wait_vm<8>();          // C2 done                  (8: MC,C3)
    QK2(0, 4, mw0);
    ISSUE_M4(4, 12);       // MD (tiles 12-15)         (12: MC,C3,MD)
    ISSUE_K2(0, 4);        //                          (16: MC,C3,MD,C4)
    wait_vm<12>();         // MC done                  (12: C3,MD,C4)
    PACK_M4(mwC, 0);
    wait_vm<8>();          // C3 done                  (8: MD,C4)
    QK2(1, 6, mw0);
    ISSUE_K2(1, 5);        //                          (12: MD,C4,C5)
    wait_vm<8>();          // MD done                  (8: C4,C5)
    PACK_M4(mwD, 4);
    mw1 = mwC | (mwD << 16);
    wait_vm<4>();          // C4 done                  (4: C5)
    QK2(0, 8, mw1);
    ISSUE_K2(0, 6);        //                          (8: C5,C6)
    wait_vm<4>();          // C5 done                  (4: C6)
    QK2(1, 10, mw1);
    ISSUE_K2(1, 7);        //                          (8: C6,C7)
    wait_vm<4>();          // C6 done                  (4: C7)
    QK2(0, 12, mw1);
    wait_vm<0>();          // C7 done
    QK2(1, 14, mw1);

    // ---- softmax: row max across lg groups, then across waves ----
    mx = fmaxf(mx, __shfl_xor(mx, 16));
    mx = fmaxf(mx, __shfl_xor(mx, 32));
    if (lane < 16) red[0][w][lr] = mx;
    __syncthreads();
    const float gm = fmaxf(fmaxf(red[0][0][lr], red[0][1][lr]),
                           fmaxf(red[0][2][lr], red[0][3][lr]));

    // ---- exp + row sum; p stays packed fp16 (unnormalized) ----
    float lsum = 0.f;
#pragma unroll
    for (int tt = 0; tt < 16; ++tt) {
        half2v a = __builtin_bit_cast(half2v, sh[tt][0]);
        half2v b = __builtin_bit_cast(half2v, sh[tt][1]);
        float p0 = __expf((float)a[0] - gm);
        float p1 = __expf((float)a[1] - gm);
        float p2 = __expf((float)b[0] - gm);
        float p3 = __expf((float)b[1] - gm);
        lsum += (p0 + p1) + (p2 + p3);
        sh[tt][0] = pk2h(p0, p1);
        sh[tt][1] = pk2h(p2, p3);
    }
    lsum += __shfl_xor(lsum, 16);
    lsum += __shfl_xor(lsum, 32);
    if (lane < 16) red[1][w][lr] = lsum;
    __syncthreads();
    const float gsum = red[1][0][lr] + red[1][1][lr] + red[1][2][lr] + red[1][3][lr];
    const float rinv = 1.0f / gsum;

    // ---- PV: V chunks of 4 loads (one c-step), dbuf ----
    const unsigned short* vp = Vt + ((size_t)bh * 64 + lr) * L_ + w * 256 + lg * 8;
    const unsigned short* vp0 = vp;
    const unsigned short* vp1 = vp + 16384;
    const unsigned short* vp2 = vp + 32768;
    const unsigned short* vp3 = vp + 49152;
    f32x4 cacc[4] = {{0,0,0,0},{0,0,0,0},{0,0,0,0},{0,0,0,0}};
    unsigned short* pb = &u.pbuf[w][0];
    half8 vv[2][4];   // [buf][nt]
#define ISSUE_V1(BUF, C) { \
    gl_h8<(C) * 64>(vv[BUF][0], vp0); gl_h8<(C) * 64>(vv[BUF][1], vp1); \
    gl_h8<(C) * 64>(vv[BUF][2], vp2); gl_h8<(C) * 64>(vv[BUF][3], vp3); }
#define PV_C(BUF, C) { \
    uint2 pr0_; pr0_.x = sh[2 * (C)][0]; pr0_.y = sh[2 * (C)][1]; \
    *reinterpret_cast<uint2*>(&pb[lr * 40 + lg * 4]) = pr0_; \
    uint2 pr1_; pr1_.x = sh[2 * (C) + 1][0]; pr1_.y = sh[2 * (C) + 1][1]; \
    *reinterpret_cast<uint2*>(&pb[lr * 40 + 16 + lg * 4]) = pr1_; \
    half8 pa_ = *reinterpret_cast<const half8*>(&pb[lr * 40 + lg * 8]); \
    cacc[0] = __builtin_amdgcn_mfma_f32_16x16x32_f16(pa_, vv[BUF][0], cacc[0], 0, 0, 0); \
    cacc[1] = __builtin_amdgcn_mfma_f32_16x16x32_f16(pa_, vv[BUF][1], cacc[1], 0, 0, 0); \
    cacc[2] = __builtin_amdgcn_mfma_f32_16x16x32_f16(pa_, vv[BUF][2], cacc[2], 0, 0, 0); \
    cacc[3] = __builtin_amdgcn_mfma_f32_16x16x32_f16(pa_, vv[BUF][3], cacc[3], 0, 0, 0); }

    ISSUE_V1(0, 0); ISSUE_V1(1, 1);          // (8: V0,V1)
    wait_vm<4>(); PV_C(0, 0); ISSUE_V1(0, 2);// (8: V1,V2)
    wait_vm<4>(); PV_C(1, 1); ISSUE_V1(1, 3);// (8: V2,V3)
    wait_vm<4>(); PV_C(0, 2); ISSUE_V1(0, 4);// (8: V3,V4)
    wait_vm<4>(); PV_C(1, 3); ISSUE_V1(1, 5);// (8: V4,V5)
    wait_vm<4>(); PV_C(0, 4); ISSUE_V1(0, 6);// (8: V5,V6)
    wait_vm<4>(); PV_C(1, 5); ISSUE_V1(1, 7);// (8: V6,V7)
    wait_vm<4>(); PV_C(0, 6);                // (4: V7)
    wait_vm<0>(); PV_C(1, 7);

    // ---- attn write pass (normalized); compiler vmem only after last wait ----
#pragma unroll
    for (int tt = 0; tt < 16; ++tt) {
        half2v a = __builtin_bit_cast(half2v, sh[tt][0]);
        half2v b = __builtin_bit_cast(half2v, sh[tt][1]);
        float4 av;
        av.x = (float)a[0] * rinv; av.y = (float)a[1] * rinv;
        av.z = (float)b[0] * rinv; av.w = (float)b[1] * rinv;
        *reinterpret_cast<float4*>(&attn_out[rowbase + w * 256 + tt * 16 + lg * 4]) = av;
    }

    // ---- combine partial contexts across waves, normalize by 1/sum ----
    __syncthreads();  // all waves done with u.pbuf before u.ctxbuf overwrites
#pragma unroll
    for (int nt = 0; nt < 4; ++nt)
#pragma unroll
        for (int r = 0; r < 4; ++r)
            u.ctxbuf[w][lg * 4 + r][nt * 16 + lr] = cacc[nt][r];
    __syncthreads();
    {
        int e = tid * 4;
        int q = e >> 6, n = e & 63;
        float gs = red[1][0][q] + red[1][1][q] + red[1][2][q] + red[1][3][q];
        float rq = 1.0f / gs;
        float4 a0 = *reinterpret_cast<float4*>(&u.ctxbuf[0][q][n]);
        float4 a1 = *reinterpret_cast<float4*>(&u.ctxbuf[1][q][n]);
        float4 a2 = *reinterpret_cast<float4*>(&u.ctxbuf[2][q][n]);
        float4 a3 = *reinterpret_cast<float4*>(&u.ctxbuf[3][q][n]);
        float4 o;
        o.x = (a0.x + a1.x + a2.x + a3.x) * rq;
        o.y = (a0.y + a1.y + a2.y + a3.y) * rq;
        o.z = (a0.z + a1.z + a2.z + a3.z) * rq;
        o.w = (a0.w + a1.w + a2.w + a3.w) * rq;
        *reinterpret_cast<float4*>(&ctx_out[((size_t)bh * L_ + q0 + q) * DK_ + n]) = o;
    }
}

extern "C" void kernel_launch(void* const* d_in, const int* in_sizes, int n_in,
                              void* d_out, int out_size, void* d_ws, size_t ws_size,
                              hipStream_t stream) {
    const float* Q = (const float*)d_in[0];
    const float* K = (const float*)d_in[1];
    const float* V = (const float*)d_in[2];
    const int* mask = (const int*)d_in[3];
    float* ctx_out = (float*)d_out;
    float* attn_out = ctx_out + (size_t)BH_ * L_ * DK_;

    unsigned short* Kh = (unsigned short*)d_ws;
    unsigned short* Vt = Kh + (size_t)BH_ * L_ * DK_;

    hipLaunchKernelGGL(prep_k, dim3(4096), dim3(256), 0, stream, K, Kh);
    hipLaunchKernelGGL(prep_v, dim3(1024), dim3(256), 0, stream, V, Vt);
    hipLaunchKernelGGL(attn_main, dim3(64, 64), dim3(256), 0, stream,
                       Q, mask, Kh, Vt, ctx_out, attn_out);
}